// Round 11
// baseline (192.615 us; speedup 1.0000x reference)
//
#include <hip/hip_runtime.h>

#define B 2
#define S 2048
#define H 768
#define NH 12
#define HD 64
#define BS (B * S)
#define LOG2E 1.4426950408889634f

typedef unsigned short u16;
typedef short short8 __attribute__((ext_vector_type(8)));
typedef float f32x4 __attribute__((ext_vector_type(4)));
typedef float f32x16 __attribute__((ext_vector_type(16)));

// fp32 -> bf16 round-to-nearest-even
__device__ __forceinline__ u16 f2bf(float f) {
    union { float f; unsigned u; } c; c.f = f;
    unsigned u = c.u + 0x7FFFu + ((c.u >> 16) & 1u);
    return (u16)(u >> 16);
}
__device__ __forceinline__ float bf2f(u16 h) {
    union { unsigned u; float f; } c; c.u = ((unsigned)h) << 16;
    return c.f;
}
__device__ __forceinline__ f32x16 zero16() {
    f32x16 v;
    #pragma unroll
    for (int i = 0; i < 16; ++i) v[i] = 0.f;
    return v;
}

// async global->LDS DMA, 16 B per lane; lds dest = wave-uniform base + lane*16
__device__ __forceinline__ void g2l16(const u16* g, u16* l) {
    __builtin_amdgcn_global_load_lds(
        (const __attribute__((address_space(1))) void*)g,
        (__attribute__((address_space(3))) void*)l, 16, 0, 0);
}

// ---------------------------------------------------------------------------
// Merged prep: blocks [0,576) transpose+convert weights (RoPE folded into
// Wq/Wk per the reference's head-indexed-table quirk; Q also folds
// 0.125*log2e); blocks [576,2112) convert hidden_states fp32->bf16.
// ---------------------------------------------------------------------------
__global__ __launch_bounds__(256) void prep_kernel(
    const float* __restrict__ hs,
    const float* __restrict__ Wq, const float* __restrict__ Wk,
    const float* __restrict__ Wv, const float* __restrict__ Wo,
    const float* __restrict__ bq, const float* __restrict__ bk,
    const float* __restrict__ cosp, const float* __restrict__ sinp,
    u16* __restrict__ hsb, u16* __restrict__ WTqkv, u16* __restrict__ WTo,
    float* __restrict__ bqk2)
{
    __shared__ float Lt[64 * 65];
    const int bid = blockIdx.x;
    const int t = threadIdx.x;

    if (bid >= 576) {                       // ---- hidden_states convert ----
        size_t i = ((size_t)(bid - 576) * 256 + t) * 8;
        float4 a = *(const float4*)(hs + i);
        float4 b = *(const float4*)(hs + i + 4);
        short8 p;
        p[0] = (short)f2bf(a.x); p[1] = (short)f2bf(a.y);
        p[2] = (short)f2bf(a.z); p[3] = (short)f2bf(a.w);
        p[4] = (short)f2bf(b.x); p[5] = (short)f2bf(b.y);
        p[6] = (short)f2bf(b.z); p[7] = (short)f2bf(b.w);
        *(short8*)(hsb + i) = p;
        return;
    }

    // ---- weight transpose (+RoPE fold for z<2) ----
    const int z   = bid / 144;
    const int rem = bid - z * 144;
    const int k0 = (rem / 12) * 64, n0 = (rem % 12) * 64;
    const float* W = (z == 0) ? Wq : (z == 1) ? Wk : (z == 2) ? Wv : Wo;
    u16* D = (z == 3) ? WTo : (WTqkv + (size_t)z * H * H);
    const int head = n0 >> 6;
    const float scl = (z == 0) ? (0.125f * LOG2E) : 1.0f;

    if (z < 2 && rem / 12 == 0 && t < 64) {   // rotated bias, once per col-tile
        const float* bs = (z == 0) ? bq : bk;
        int d = t;
        int pd = (d < 32) ? (2 * d + 1) : (2 * (d - 32));
        float sv = ((d < 32) ? -1.f : 1.f) * sinp[head * HD + d];
        float cv = cosp[head * HD + d];
        bqk2[z * H + n0 + d] = scl * (cv * bs[n0 + d] + sv * bs[n0 + pd]);
    }

    #pragma unroll
    for (int u = 0; u < 4; ++u) {
        int f = t + u * 256;
        int r = f >> 4, c4 = (f & 15) * 4;
        float4 w = *(const float4*)(W + (size_t)(k0 + r) * H + n0 + c4);
        Lt[r * 65 + c4 + 0] = w.x; Lt[r * 65 + c4 + 1] = w.y;
        Lt[r * 65 + c4 + 2] = w.z; Lt[r * 65 + c4 + 3] = w.w;
    }
    __syncthreads();
    #pragma unroll
    for (int u = 0; u < 4; ++u) {
        int f = t + u * 256;
        int n = f >> 4, k4 = (f & 15) * 4;
        ushort4 p;
        if (z < 2) {
            int pn = (n < 32) ? (2 * n + 1) : (2 * (n - 32));
            float cv = scl * cosp[head * HD + n];
            float sv = scl * ((n < 32) ? -1.f : 1.f) * sinp[head * HD + n];
            p.x = f2bf(cv * Lt[(k4 + 0) * 65 + n] + sv * Lt[(k4 + 0) * 65 + pn]);
            p.y = f2bf(cv * Lt[(k4 + 1) * 65 + n] + sv * Lt[(k4 + 1) * 65 + pn]);
            p.z = f2bf(cv * Lt[(k4 + 2) * 65 + n] + sv * Lt[(k4 + 2) * 65 + pn]);
            p.w = f2bf(cv * Lt[(k4 + 3) * 65 + n] + sv * Lt[(k4 + 3) * 65 + pn]);
        } else {
            p.x = f2bf(Lt[(k4 + 0) * 65 + n]);
            p.y = f2bf(Lt[(k4 + 1) * 65 + n]);
            p.z = f2bf(Lt[(k4 + 2) * 65 + n]);
            p.w = f2bf(Lt[(k4 + 3) * 65 + n]);
        }
        *(ushort4*)(D + (size_t)(n0 + n) * H + k0 + k4) = p;
    }
}

// ---------------------------------------------------------------------------
// Fused QKV GEMM, bf16 MFMA, DMA double-buffered (one barrier per K-slab),
// XOR-swizzled unpadded LDS. 1-D grid, m-block = bid % 32: since 32 = 0 mod 8,
// all 18 n-blocks of an m-slice land on ONE XCD -> A rows stay in that XCD's
// L2 (per-XCD set = 0.8 MB A-slice + 3.5 MB shared B).
// ---------------------------------------------------------------------------
__global__ __launch_bounds__(256) void gemm_qkv_kernel(
    const u16* __restrict__ A, const u16* __restrict__ BT,
    const float* __restrict__ bqk2, const float* __restrict__ bv,
    u16* __restrict__ Qb, u16* __restrict__ Kb, u16* __restrict__ VT)
{
    __shared__ alignas(16) u16 Abuf[2][128 * 64];
    __shared__ alignas(16) u16 Bbuf[2][128 * 64];

    const int tid  = threadIdx.x;
    const int w    = tid >> 6;
    const int lane = tid & 63;
    const int quad = lane >> 4;
    const int l15  = lane & 15;
    const int wm = (w & 1) * 64, wn = (w >> 1) * 64;
    const int m0 = (blockIdx.x & 31) * 128;   // XCD-local m-slice
    const int n0 = (blockIdx.x >> 5) * 128;
    const int NK = H / 64;   // 12

    int srow[4], slc[4];
    #pragma unroll
    for (int u = 0; u < 4; ++u) {
        int s = u * 256 + tid;
        srow[u] = s >> 3;
        slc[u]  = (s & 7) ^ (srow[u] & 7);
    }

    #define QSTAGE(IT, NB)                                                    \
        _Pragma("unroll")                                                     \
        for (int u = 0; u < 4; ++u) {                                         \
            g2l16(A  + (size_t)(m0 + srow[u]) * H + (IT) * 64 + slc[u] * 8,   \
                  &Abuf[NB][(u * 256 + w * 64) * 8]);                         \
            g2l16(BT + (size_t)(n0 + srow[u]) * H + (IT) * 64 + slc[u] * 8,   \
                  &Bbuf[NB][(u * 256 + w * 64) * 8]);                         \
        }

    QSTAGE(0, 0)

    f32x4 acc[4][4];
    #pragma unroll
    for (int i = 0; i < 4; ++i)
        #pragma unroll
        for (int j = 0; j < 4; ++j) acc[i][j] = (f32x4){0.f, 0.f, 0.f, 0.f};

    for (int it = 0; it < NK; ++it) {
        const int cur = it & 1;
        __syncthreads();                       // drains DMA for buffer cur
        if (it + 1 < NK) { QSTAGE(it + 1, cur ^ 1) }

        const u16* Ac = Abuf[cur];
        const u16* Bc = Bbuf[cur];
        #pragma unroll
        for (int kc = 0; kc < 2; ++kc) {
            const int ch = kc * 4 + quad;
            short8 af[4], bf[4];
            #pragma unroll
            for (int mi = 0; mi < 4; ++mi) {
                int row = wm + mi * 16 + l15;
                af[mi] = *(const short8*)&Ac[row * 64 + (ch ^ (row & 7)) * 8];
            }
            #pragma unroll
            for (int ni = 0; ni < 4; ++ni) {
                int row = wn + ni * 16 + l15;
                bf[ni] = *(const short8*)&Bc[row * 64 + (ch ^ (row & 7)) * 8];
            }
            #pragma unroll
            for (int mi = 0; mi < 4; ++mi)
                #pragma unroll
                for (int ni = 0; ni < 4; ++ni)
                    acc[mi][ni] = __builtin_amdgcn_mfma_f32_16x16x32_bf16(
                        af[mi], bf[ni], acc[mi][ni], 0, 0, 0);
        }
    }
    #undef QSTAGE

    #pragma unroll
    for (int mi = 0; mi < 4; ++mi) {
        const int mbase = m0 + wm + mi * 16 + quad * 4;
        #pragma unroll
        for (int ni = 0; ni < 4; ++ni) {
            const int col = n0 + wn + ni * 16 + l15;      // 0..2303
            const int which = col / H;
            const int c = col - which * H;
            const int h = c >> 6, d = c & 63;
            if (which == 2) {
                const float bias = bv[c];
                const int b_ = mbase >> 11, s = mbase & (S - 1);
                ushort4 pk;
                pk.x = f2bf(acc[mi][ni][0] + bias);
                pk.y = f2bf(acc[mi][ni][1] + bias);
                pk.z = f2bf(acc[mi][ni][2] + bias);
                pk.w = f2bf(acc[mi][ni][3] + bias);
                *(ushort4*)&VT[(((size_t)b_ * NH + h) * HD + d) * S + s] = pk;
            } else {
                u16* dst = (which == 0) ? Qb : Kb;
                const float bias = bqk2[which * H + c];   // rotated (+scaled)
                #pragma unroll
                for (int r = 0; r < 4; ++r) {
                    int m = mbase + r;
                    int b_ = m >> 11, s = m & (S - 1);
                    dst[(((size_t)b_ * NH + h) * S + s) * HD + d] =
                        f2bf(acc[mi][ni][r] + bias);
                }
            }
        }
    }
}

// ---------------------------------------------------------------------------
// Output projection: out[4096,768] fp32 = ctxb @ WTo^T + bo. 128x64 tile,
// DMA double-buffered, XOR-swizzled LDS. 1-D grid, m-block = bid % 32
// (XCD-local ctx rows; WTo 1.2 MB shared).
// ---------------------------------------------------------------------------
__global__ __launch_bounds__(256) void gemm_out_kernel(
    const u16* __restrict__ A, const u16* __restrict__ BT,
    const float* __restrict__ bo, float* __restrict__ out)
{
    __shared__ alignas(16) u16 Abuf[2][128 * 64];
    __shared__ alignas(16) u16 Bbuf[2][64 * 64];

    const int tid  = threadIdx.x;
    const int w    = tid >> 6;
    const int lane = tid & 63;
    const int quad = lane >> 4;
    const int l15  = lane & 15;
    const int wm = (w & 1) * 64, wn = (w >> 1) * 32;
    const int m0 = (blockIdx.x & 31) * 128;   // XCD-local m-slice
    const int n0 = (blockIdx.x >> 5) * 64;
    const int NK = H / 64;

    int srow[4], slc[4];
    #pragma unroll
    for (int u = 0; u < 4; ++u) {
        int s = u * 256 + tid;
        srow[u] = s >> 3;
        slc[u]  = (s & 7) ^ (srow[u] & 7);
    }

    #define OSTAGE(IT, NB)                                                    \
        _Pragma("unroll")                                                     \
        for (int u = 0; u < 4; ++u)                                           \
            g2l16(A + (size_t)(m0 + srow[u]) * H + (IT) * 64 + slc[u] * 8,    \
                  &Abuf[NB][(u * 256 + w * 64) * 8]);                         \
        _Pragma("unroll")                                                     \
        for (int u = 0; u < 2; ++u)                                           \
            g2l16(BT + (size_t)(n0 + srow[u]) * H + (IT) * 64 + slc[u] * 8,   \
                  &Bbuf[NB][(u * 256 + w * 64) * 8]);

    OSTAGE(0, 0)

    f32x4 acc[4][2];
    #pragma unroll
    for (int i = 0; i < 4; ++i)
        #pragma unroll
        for (int j = 0; j < 2; ++j) acc[i][j] = (f32x4){0.f, 0.f, 0.f, 0.f};

    for (int it = 0; it < NK; ++it) {
        const int cur = it & 1;
        __syncthreads();
        if (it + 1 < NK) { OSTAGE(it + 1, cur ^ 1) }

        const u16* Ac = Abuf[cur];
        const u16* Bc = Bbuf[cur];
        #pragma unroll
        for (int kc = 0; kc < 2; ++kc) {
            const int ch = kc * 4 + quad;
            short8 af[4], bf[2];
            #pragma unroll
            for (int mi = 0; mi < 4; ++mi) {
                int row = wm + mi * 16 + l15;
                af[mi] = *(const short8*)&Ac[row * 64 + (ch ^ (row & 7)) * 8];
            }
            #pragma unroll
            for (int ni = 0; ni < 2; ++ni) {
                int row = wn + ni * 16 + l15;
                bf[ni] = *(const short8*)&Bc[row * 64 + (ch ^ (row & 7)) * 8];
            }
            #pragma unroll
            for (int mi = 0; mi < 4; ++mi)
                #pragma unroll
                for (int ni = 0; ni < 2; ++ni)
                    acc[mi][ni] = __builtin_amdgcn_mfma_f32_16x16x32_bf16(
                        af[mi], bf[ni], acc[mi][ni], 0, 0, 0);
        }
    }
    #undef OSTAGE

    #pragma unroll
    for (int mi = 0; mi < 4; ++mi) {
        const int mbase = m0 + wm + mi * 16 + quad * 4;
        #pragma unroll
        for (int ni = 0; ni < 2; ++ni) {
            const int col = n0 + wn + ni * 16 + l15;
            const float bias = bo[col];
            #pragma unroll
            for (int r = 0; r < 4; ++r)
                out[(size_t)(mbase + r) * H + col] = acc[mi][ni][r] + bias;
        }
    }
}

// ---------------------------------------------------------------------------
// Flash attention, bf16 32x32x16 MFMA, exp2 no-max softmax, DMA-dbuf K/V.
// 1-D grid 768, bn = bid % 24: 24 = 0 mod 8 -> all 32 q-blocks of a head on
// ONE XCD; per-XCD K/V/Q working set ~4 MB = L2 -> DMA becomes L2-hit.
// V-fragment LDS reads hoisted before the exp/P-write VALU burst.
// ---------------------------------------------------------------------------
__global__ __launch_bounds__(256) void attn_mfma_kernel(
    const u16* __restrict__ Q, const u16* __restrict__ K,
    const u16* __restrict__ VT, const float* __restrict__ mask,
    u16* __restrict__ ctx)
{
    __shared__ alignas(16) u16 smem[21504];
    u16* const Kbase = smem;
    u16* const Vbase = smem + 8192;
    u16* const Psw   = smem + 16384 + (threadIdx.x >> 6) * 1280;

    const int tid  = threadIdx.x;
    const int w    = tid >> 6;
    const int lane = tid & 63;
    const int l31  = lane & 31;
    const int h5   = lane >> 5;
    const int rh   = w & 1;   // row-half
    const int kh   = w >> 1;  // key-half
    const int bid = blockIdx.x;
    const int bn = bid % 24;              // XCD-local head
    const int q0 = (bid / 24) * 64;
    const int b = bn / NH, hh = bn % NH;
    const int NT = S / 64;

    short8 qa[4];
    {
        const u16* Qp = Q + ((size_t)bn * S + q0 + rh * 32 + l31) * HD + h5 * 8;
        #pragma unroll
        for (int kc = 0; kc < 4; ++kc)
            qa[kc] = *(const short8*)(Qp + kc * 16);
    }

    const u16* Kg = K + (size_t)bn * S * HD;
    const u16* Vg = VT + (size_t)bn * HD * S;
    const float* mrow = mask + (size_t)b * S;

    int srow[2], slc[2];
    #pragma unroll
    for (int u = 0; u < 2; ++u) {
        int s = u * 256 + tid;
        srow[u] = s >> 3;
        slc[u]  = (s & 7) ^ (srow[u] & 7);
    }

    #define STAGE(JT, NB)                                                     \
        _Pragma("unroll")                                                     \
        for (int u = 0; u < 2; ++u) {                                         \
            g2l16(Kg + (size_t)((JT) * 64 + srow[u]) * HD + slc[u] * 8,       \
                  Kbase + (NB) * 4096 + (u * 256 + w * 64) * 8);              \
            g2l16(Vg + (size_t)srow[u] * S + (JT) * 64 + slc[u] * 8,          \
                  Vbase + (NB) * 4096 + (u * 256 + w * 64) * 8);              \
        }

    STAGE(0, 0)

    f32x16 o0 = zero16(), o1 = zero16();
    float l_p[16];
    #pragma unroll
    for (int i = 0; i < 16; ++i) l_p[i] = 0.f;

    for (int jt = 0; jt < NT; ++jt) {
        const int cur = jt & 1;
        const float mv = mrow[jt * 64 + kh * 32 + l31];
        __syncthreads();
        if (jt + 1 < NT) { STAGE(jt + 1, cur ^ 1) }

        const u16* Kc = Kbase + cur * 4096;
        const u16* Vc = Vbase + cur * 4096;

        f32x16 sc = zero16();
        {
            const int krow = kh * 32 + l31;
            const int sw = krow & 7;
            #pragma unroll
            for (int kc = 0; kc < 4; ++kc) {
                const short8 kb =
                    *(const short8*)&Kc[krow * 64 + ((kc * 2 + h5) ^ sw) * 8];
                sc = __builtin_amdgcn_mfma_f32_32x32x16_bf16(qa[kc], kb, sc, 0, 0, 0);
            }
        }

        // V fragments issued BEFORE the exp burst: DS latency hides under VALU
        short8 vb[2][2];
        #pragma unroll
        for (int nt = 0; nt < 2; ++nt) {
            const int vrow = nt * 32 + l31;
            const int sw = vrow & 7;
            vb[nt][0] = *(const short8*)&Vc[vrow * 64 + ((kh * 4 + h5) ^ sw) * 8];
            vb[nt][1] = *(const short8*)&Vc[vrow * 64 + ((kh * 4 + 2 + h5) ^ sw) * 8];
        }

        const float mt = (1.0f - mv) * (-10000.0f * LOG2E);
        #pragma unroll
        for (int reg = 0; reg < 16; ++reg) {
            float p = __builtin_amdgcn_exp2f(sc[reg] + mt);
            l_p[reg] += p;
            const int r32 = (reg & 3) + 8 * (reg >> 2) + 4 * h5;
            Psw[r32 * 40 + l31] = f2bf(p);
        }

        asm volatile("s_waitcnt lgkmcnt(0)" ::: "memory");

        const short8 pa0 = *(const short8*)&Psw[l31 * 40 + h5 * 8];
        const short8 pa1 = *(const short8*)&Psw[l31 * 40 + 16 + h5 * 8];

        o0 = __builtin_amdgcn_mfma_f32_32x32x16_bf16(pa0, vb[0][0], o0, 0, 0, 0);
        o0 = __builtin_amdgcn_mfma_f32_32x32x16_bf16(pa1, vb[0][1], o0, 0, 0, 0);
        o1 = __builtin_amdgcn_mfma_f32_32x32x16_bf16(pa0, vb[1][0], o1, 0, 0, 0);
        o1 = __builtin_amdgcn_mfma_f32_32x32x16_bf16(pa1, vb[1][1], o1, 0, 0, 0);
    }
    #undef STAGE

    #pragma unroll
    for (int reg = 0; reg < 16; ++reg) {
        #pragma unroll
        for (int off = 16; off >= 1; off >>= 1)
            l_p[reg] += __shfl_xor(l_p[reg], off, 32);
    }

    __syncthreads();
    float* cb = (float*)smem;
    float* lb = (float*)(smem + 16384);

    if (kh == 1) {
        float* c = cb + rh * 2048;
        #pragma unroll
        for (int reg = 0; reg < 16; ++reg) {
            float2 v = make_float2(o0[reg], o1[reg]);
            *(float2*)&c[reg * 128 + lane * 2] = v;
        }
        if (l31 == 0) {
            #pragma unroll
            for (int reg = 0; reg < 16; ++reg)
                lb[rh * 32 + h5 * 16 + reg] = l_p[reg];
        }
    }
    __syncthreads();
    if (kh == 0) {
        const float* c = cb + rh * 2048;
        #pragma unroll
        for (int reg = 0; reg < 16; ++reg) {
            float2 po = *(const float2*)&c[reg * 128 + lane * 2];
            float lt = l_p[reg] + lb[rh * 32 + h5 * 16 + reg];
            float inv = 1.0f / lt;
            const int r32 = (reg & 3) + 8 * (reg >> 2) + 4 * h5;
            const int s = q0 + rh * 32 + r32;
            u16* dst = ctx + ((size_t)b * S + s) * H + hh * 64;
            dst[l31]      = f2bf((o0[reg] + po.x) * inv);
            dst[32 + l31] = f2bf((o1[reg] + po.y) * inv);
        }
    }
}

// ---------------------------------------------------------------------------
extern "C" void kernel_launch(void* const* d_in, const int* in_sizes, int n_in,
                              void* d_out, int out_size, void* d_ws, size_t ws_size,
                              hipStream_t stream)
{
    const float* hs   = (const float*)d_in[0];
    const float* mask = (const float*)d_in[1];
    const float* Wq   = (const float*)d_in[2];
    const float* bq   = (const float*)d_in[3];
    const float* Wk   = (const float*)d_in[4];
    const float* bk   = (const float*)d_in[5];
    const float* Wv   = (const float*)d_in[6];
    const float* bv   = (const float*)d_in[7];
    const float* Wo   = (const float*)d_in[8];
    const float* bo   = (const float*)d_in[9];
    const float* cosp = (const float*)d_in[10];
    const float* sinp = (const float*)d_in[11];
    float* out = (float*)d_out;

    const size_t per = (size_t)B * NH * S * HD;   // 3,145,728
    u16* ws    = (u16*)d_ws;
    u16* hsb   = ws;                              // bf16 hidden  [BS,H]
    u16* WTqkv = hsb + per;                       // bf16 [2304,768] (Q/K rotated)
    u16* WTo   = WTqkv + (size_t)3 * H * H;       // bf16 [768,768]
    u16* Qb    = WTo + (size_t)H * H;             // bf16 [B,NH,S,HD] final
    u16* Kb    = Qb + per;                        // bf16 final
    u16* VT    = Kb + per;                        // bf16 [B,NH,HD,S]
    u16* ctxb  = VT + per;                        // bf16 [BS,H]
    float* bqk2 = (float*)(ctxb + per);           // rotated biases [2*H]

    prep_kernel<<<576 + (BS * H) / 2048, 256, 0, stream>>>(
        hs, Wq, Wk, Wv, Wo, bq, bk, cosp, sinp, hsb, WTqkv, WTo, bqk2);

    gemm_qkv_kernel<<<(BS / 128) * (2304 / 128), 256, 0, stream>>>(
        hsb, WTqkv, bqk2, bv, Qb, Kb, VT);

    attn_mfma_kernel<<<(S / 64) * (B * NH), 256, 0, stream>>>(
        Qb, Kb, VT, mask, ctxb);

    gemm_out_kernel<<<(BS / 128) * (H / 64), 256, 0, stream>>>(
        ctxb, WTo, bo, out);
}

// Round 13
// 188.679 us; speedup vs baseline: 1.0209x; 1.0209x over previous
//
#include <hip/hip_runtime.h>

#define B 2
#define S 2048
#define H 768
#define NH 12
#define HD 64
#define BS (B * S)
#define LOG2E 1.4426950408889634f

typedef unsigned short u16;
typedef unsigned int u32;
typedef short short8 __attribute__((ext_vector_type(8)));
typedef float f32x4 __attribute__((ext_vector_type(4)));
typedef float f32x16 __attribute__((ext_vector_type(16)));

// fp32 -> bf16 round-to-nearest-even
__device__ __forceinline__ u16 f2bf(float f) {
    union { float f; unsigned u; } c; c.f = f;
    unsigned u = c.u + 0x7FFFu + ((c.u >> 16) & 1u);
    return (u16)(u >> 16);
}
__device__ __forceinline__ float bf2f(u16 h) {
    union { unsigned u; float f; } c; c.u = ((unsigned)h) << 16;
    return c.f;
}
__device__ __forceinline__ f32x16 zero16() {
    f32x16 v;
    #pragma unroll
    for (int i = 0; i < 16; ++i) v[i] = 0.f;
    return v;
}
union pk4 { uint4 u; short8 s; };

// async global->LDS DMA, 16 B per lane; lds dest = wave-uniform base + lane*16
__device__ __forceinline__ void g2l16(const u16* g, u16* l) {
    __builtin_amdgcn_global_load_lds(
        (const __attribute__((address_space(1))) void*)g,
        (__attribute__((address_space(3))) void*)l, 16, 0, 0);
}

// ---------------------------------------------------------------------------
// Merged prep: blocks [0,576) transpose+convert weights (RoPE folded into
// Wq/Wk per the reference's head-indexed-table quirk; Q also folds
// 0.125*log2e); blocks [576,2112) convert hidden_states fp32->bf16.
// ---------------------------------------------------------------------------
__global__ __launch_bounds__(256) void prep_kernel(
    const float* __restrict__ hs,
    const float* __restrict__ Wq, const float* __restrict__ Wk,
    const float* __restrict__ Wv, const float* __restrict__ Wo,
    const float* __restrict__ bq, const float* __restrict__ bk,
    const float* __restrict__ cosp, const float* __restrict__ sinp,
    u16* __restrict__ hsb, u16* __restrict__ WTqkv, u16* __restrict__ WTo,
    float* __restrict__ bqk2)
{
    __shared__ float Lt[64 * 65];
    const int bid = blockIdx.x;
    const int t = threadIdx.x;

    if (bid >= 576) {                       // ---- hidden_states convert ----
        size_t i = ((size_t)(bid - 576) * 256 + t) * 8;
        float4 a = *(const float4*)(hs + i);
        float4 b = *(const float4*)(hs + i + 4);
        short8 p;
        p[0] = (short)f2bf(a.x); p[1] = (short)f2bf(a.y);
        p[2] = (short)f2bf(a.z); p[3] = (short)f2bf(a.w);
        p[4] = (short)f2bf(b.x); p[5] = (short)f2bf(b.y);
        p[6] = (short)f2bf(b.z); p[7] = (short)f2bf(b.w);
        *(short8*)(hsb + i) = p;
        return;
    }

    // ---- weight transpose (+RoPE fold for z<2) ----
    const int z   = bid / 144;
    const int rem = bid - z * 144;
    const int k0 = (rem / 12) * 64, n0 = (rem % 12) * 64;
    const float* W = (z == 0) ? Wq : (z == 1) ? Wk : (z == 2) ? Wv : Wo;
    u16* D = (z == 3) ? WTo : (WTqkv + (size_t)z * H * H);
    const int head = n0 >> 6;
    const float scl = (z == 0) ? (0.125f * LOG2E) : 1.0f;

    if (z < 2 && rem / 12 == 0 && t < 64) {   // rotated bias, once per col-tile
        const float* bs = (z == 0) ? bq : bk;
        int d = t;
        int pd = (d < 32) ? (2 * d + 1) : (2 * (d - 32));
        float sv = ((d < 32) ? -1.f : 1.f) * sinp[head * HD + d];
        float cv = cosp[head * HD + d];
        bqk2[z * H + n0 + d] = scl * (cv * bs[n0 + d] + sv * bs[n0 + pd]);
    }

    #pragma unroll
    for (int u = 0; u < 4; ++u) {
        int f = t + u * 256;
        int r = f >> 4, c4 = (f & 15) * 4;
        float4 w = *(const float4*)(W + (size_t)(k0 + r) * H + n0 + c4);
        Lt[r * 65 + c4 + 0] = w.x; Lt[r * 65 + c4 + 1] = w.y;
        Lt[r * 65 + c4 + 2] = w.z; Lt[r * 65 + c4 + 3] = w.w;
    }
    __syncthreads();
    #pragma unroll
    for (int u = 0; u < 4; ++u) {
        int f = t + u * 256;
        int n = f >> 4, k4 = (f & 15) * 4;
        ushort4 p;
        if (z < 2) {
            int pn = (n < 32) ? (2 * n + 1) : (2 * (n - 32));
            float cv = scl * cosp[head * HD + n];
            float sv = scl * ((n < 32) ? -1.f : 1.f) * sinp[head * HD + n];
            p.x = f2bf(cv * Lt[(k4 + 0) * 65 + n] + sv * Lt[(k4 + 0) * 65 + pn]);
            p.y = f2bf(cv * Lt[(k4 + 1) * 65 + n] + sv * Lt[(k4 + 1) * 65 + pn]);
            p.z = f2bf(cv * Lt[(k4 + 2) * 65 + n] + sv * Lt[(k4 + 2) * 65 + pn]);
            p.w = f2bf(cv * Lt[(k4 + 3) * 65 + n] + sv * Lt[(k4 + 3) * 65 + pn]);
        } else {
            p.x = f2bf(Lt[(k4 + 0) * 65 + n]);
            p.y = f2bf(Lt[(k4 + 1) * 65 + n]);
            p.z = f2bf(Lt[(k4 + 2) * 65 + n]);
            p.w = f2bf(Lt[(k4 + 3) * 65 + n]);
        }
        *(ushort4*)(D + (size_t)(n0 + n) * H + k0 + k4) = p;
    }
}

// ---------------------------------------------------------------------------
// Fused QKV GEMM, bf16 MFMA, DMA double-buffered (one barrier per K-slab),
// XOR-swizzled unpadded LDS. 1-D grid, m-block = bid % 32 (XCD-local A rows).
// ---------------------------------------------------------------------------
__global__ __launch_bounds__(256) void gemm_qkv_kernel(
    const u16* __restrict__ A, const u16* __restrict__ BT,
    const float* __restrict__ bqk2, const float* __restrict__ bv,
    u16* __restrict__ Qb, u16* __restrict__ Kb, u16* __restrict__ VT)
{
    __shared__ alignas(16) u16 Abuf[2][128 * 64];
    __shared__ alignas(16) u16 Bbuf[2][128 * 64];

    const int tid  = threadIdx.x;
    const int w    = tid >> 6;
    const int lane = tid & 63;
    const int quad = lane >> 4;
    const int l15  = lane & 15;
    const int wm = (w & 1) * 64, wn = (w >> 1) * 64;
    const int m0 = (blockIdx.x & 31) * 128;   // XCD-local m-slice
    const int n0 = (blockIdx.x >> 5) * 128;
    const int NK = H / 64;   // 12

    int srow[4], slc[4];
    #pragma unroll
    for (int u = 0; u < 4; ++u) {
        int s = u * 256 + tid;
        srow[u] = s >> 3;
        slc[u]  = (s & 7) ^ (srow[u] & 7);
    }

    #define QSTAGE(IT, NB)                                                    \
        _Pragma("unroll")                                                     \
        for (int u = 0; u < 4; ++u) {                                         \
            g2l16(A  + (size_t)(m0 + srow[u]) * H + (IT) * 64 + slc[u] * 8,   \
                  &Abuf[NB][(u * 256 + w * 64) * 8]);                         \
            g2l16(BT + (size_t)(n0 + srow[u]) * H + (IT) * 64 + slc[u] * 8,   \
                  &Bbuf[NB][(u * 256 + w * 64) * 8]);                         \
        }

    QSTAGE(0, 0)

    f32x4 acc[4][4];
    #pragma unroll
    for (int i = 0; i < 4; ++i)
        #pragma unroll
        for (int j = 0; j < 4; ++j) acc[i][j] = (f32x4){0.f, 0.f, 0.f, 0.f};

    for (int it = 0; it < NK; ++it) {
        const int cur = it & 1;
        __syncthreads();                       // drains DMA for buffer cur
        if (it + 1 < NK) { QSTAGE(it + 1, cur ^ 1) }

        const u16* Ac = Abuf[cur];
        const u16* Bc = Bbuf[cur];
        #pragma unroll
        for (int kc = 0; kc < 2; ++kc) {
            const int ch = kc * 4 + quad;
            short8 af[4], bf[4];
            #pragma unroll
            for (int mi = 0; mi < 4; ++mi) {
                int row = wm + mi * 16 + l15;
                af[mi] = *(const short8*)&Ac[row * 64 + (ch ^ (row & 7)) * 8];
            }
            #pragma unroll
            for (int ni = 0; ni < 4; ++ni) {
                int row = wn + ni * 16 + l15;
                bf[ni] = *(const short8*)&Bc[row * 64 + (ch ^ (row & 7)) * 8];
            }
            #pragma unroll
            for (int mi = 0; mi < 4; ++mi)
                #pragma unroll
                for (int ni = 0; ni < 4; ++ni)
                    acc[mi][ni] = __builtin_amdgcn_mfma_f32_16x16x32_bf16(
                        af[mi], bf[ni], acc[mi][ni], 0, 0, 0);
        }
    }
    #undef QSTAGE

    #pragma unroll
    for (int mi = 0; mi < 4; ++mi) {
        const int mbase = m0 + wm + mi * 16 + quad * 4;
        #pragma unroll
        for (int ni = 0; ni < 4; ++ni) {
            const int col = n0 + wn + ni * 16 + l15;      // 0..2303
            const int which = col / H;
            const int c = col - which * H;
            const int h = c >> 6, d = c & 63;
            if (which == 2) {
                const float bias = bv[c];
                const int b_ = mbase >> 11, s = mbase & (S - 1);
                ushort4 pk;
                pk.x = f2bf(acc[mi][ni][0] + bias);
                pk.y = f2bf(acc[mi][ni][1] + bias);
                pk.z = f2bf(acc[mi][ni][2] + bias);
                pk.w = f2bf(acc[mi][ni][3] + bias);
                *(ushort4*)&VT[(((size_t)b_ * NH + h) * HD + d) * S + s] = pk;
            } else {
                u16* dst = (which == 0) ? Qb : Kb;
                const float bias = bqk2[which * H + c];   // rotated (+scaled)
                #pragma unroll
                for (int r = 0; r < 4; ++r) {
                    int m = mbase + r;
                    int b_ = m >> 11, s = m & (S - 1);
                    dst[(((size_t)b_ * NH + h) * S + s) * HD + d] =
                        f2bf(acc[mi][ni][r] + bias);
                }
            }
        }
    }
}

// ---------------------------------------------------------------------------
// Output projection: out[4096,768] fp32 = ctxb @ WTo^T + bo. 128x64 tile,
// DMA double-buffered, XOR-swizzled LDS, m-block = bid % 32 (XCD-local).
// ---------------------------------------------------------------------------
__global__ __launch_bounds__(256) void gemm_out_kernel(
    const u16* __restrict__ A, const u16* __restrict__ BT,
    const float* __restrict__ bo, float* __restrict__ out)
{
    __shared__ alignas(16) u16 Abuf[2][128 * 64];
    __shared__ alignas(16) u16 Bbuf[2][64 * 64];

    const int tid  = threadIdx.x;
    const int w    = tid >> 6;
    const int lane = tid & 63;
    const int quad = lane >> 4;
    const int l15  = lane & 15;
    const int wm = (w & 1) * 64, wn = (w >> 1) * 32;
    const int m0 = (blockIdx.x & 31) * 128;   // XCD-local m-slice
    const int n0 = (blockIdx.x >> 5) * 64;
    const int NK = H / 64;

    int srow[4], slc[4];
    #pragma unroll
    for (int u = 0; u < 4; ++u) {
        int s = u * 256 + tid;
        srow[u] = s >> 3;
        slc[u]  = (s & 7) ^ (srow[u] & 7);
    }

    #define OSTAGE(IT, NB)                                                    \
        _Pragma("unroll")                                                     \
        for (int u = 0; u < 4; ++u)                                           \
            g2l16(A + (size_t)(m0 + srow[u]) * H + (IT) * 64 + slc[u] * 8,    \
                  &Abuf[NB][(u * 256 + w * 64) * 8]);                         \
        _Pragma("unroll")                                                     \
        for (int u = 0; u < 2; ++u)                                           \
            g2l16(BT + (size_t)(n0 + srow[u]) * H + (IT) * 64 + slc[u] * 8,   \
                  &Bbuf[NB][(u * 256 + w * 64) * 8]);

    OSTAGE(0, 0)

    f32x4 acc[4][2];
    #pragma unroll
    for (int i = 0; i < 4; ++i)
        #pragma unroll
        for (int j = 0; j < 2; ++j) acc[i][j] = (f32x4){0.f, 0.f, 0.f, 0.f};

    for (int it = 0; it < NK; ++it) {
        const int cur = it & 1;
        __syncthreads();
        if (it + 1 < NK) { OSTAGE(it + 1, cur ^ 1) }

        const u16* Ac = Abuf[cur];
        const u16* Bc = Bbuf[cur];
        #pragma unroll
        for (int kc = 0; kc < 2; ++kc) {
            const int ch = kc * 4 + quad;
            short8 af[4], bf[2];
            #pragma unroll
            for (int mi = 0; mi < 4; ++mi) {
                int row = wm + mi * 16 + l15;
                af[mi] = *(const short8*)&Ac[row * 64 + (ch ^ (row & 7)) * 8];
            }
            #pragma unroll
            for (int ni = 0; ni < 2; ++ni) {
                int row = wn + ni * 16 + l15;
                bf[ni] = *(const short8*)&Bc[row * 64 + (ch ^ (row & 7)) * 8];
            }
            #pragma unroll
            for (int mi = 0; mi < 4; ++mi)
                #pragma unroll
                for (int ni = 0; ni < 2; ++ni)
                    acc[mi][ni] = __builtin_amdgcn_mfma_f32_16x16x32_bf16(
                        af[mi], bf[ni], acc[mi][ni], 0, 0, 0);
        }
    }
    #undef OSTAGE

    #pragma unroll
    for (int mi = 0; mi < 4; ++mi) {
        const int mbase = m0 + wm + mi * 16 + quad * 4;
        #pragma unroll
        for (int ni = 0; ni < 2; ++ni) {
            const int col = n0 + wn + ni * 16 + l15;
            const float bias = bo[col];
            #pragma unroll
            for (int r = 0; r < 4; ++r)
                out[(size_t)(mbase + r) * H + col] = acc[mi][ni][r] + bias;
        }
    }
}

// ---------------------------------------------------------------------------
// Flash attention, TRANSPOSED-S formulation: sc^T = mfma(A=K, B=Q) puts
// lane = qrow, regs = keys. P^T feeds PV as the B-operand via a half-wave
// exchange of 4 packed dwords (__shfl_xor 32) — no LDS P round-trip.
// Mask add is a 5th MFMA (A = mt[key] at k=0, B = 1). O^T = mfma(A=V^T,
// B=P^T): lane = qrow, regs = dims -> contiguous ushort4 ctx stores.
// FIX vs round 12: lb was at smem+32768 (u16 units = byte 65536, past the
// 43008-byte alloc AND the 64 KB LDS aperture -> memory fault, stream died).
// Now at smem+16384 (byte 32768; cb uses bytes 0..16383).
// ---------------------------------------------------------------------------
__global__ __launch_bounds__(256) void attn_mfma_kernel(
    const u16* __restrict__ Q, const u16* __restrict__ K,
    const u16* __restrict__ VT, const float* __restrict__ mask,
    u16* __restrict__ ctx)
{
    __shared__ alignas(16) u16 smem[21504];
    u16* const Kbase = smem;
    u16* const Vbase = smem + 8192;

    const int tid  = threadIdx.x;
    const int w    = tid >> 6;
    const int lane = tid & 63;
    const int l31  = lane & 31;
    const int h5   = lane >> 5;
    const int rh   = w & 1;   // row-half
    const int kh   = w >> 1;  // key-half
    const int bid = blockIdx.x;
    const int bn = bid % 24;              // XCD-local head
    const int q0 = (bid / 24) * 64;
    const int b = bn / NH, hh = bn % NH;
    const int NT = S / 64;

    // Q B-fragments: lane n = l31 = qrow, k = kc*16 + h5*8 + j
    short8 qa[4];
    {
        const u16* Qp = Q + ((size_t)bn * S + q0 + rh * 32 + l31) * HD + h5 * 8;
        #pragma unroll
        for (int kc = 0; kc < 4; ++kc)
            qa[kc] = *(const short8*)(Qp + kc * 16);
    }

    // constant B-frag for the mask MFMA: B[k=0][n]=1
    short8 oneb = {};
    if (h5 == 0) oneb[0] = (short)0x3F80;   // bf16 1.0

    const u16* Kg = K + (size_t)bn * S * HD;
    const u16* Vg = VT + (size_t)bn * HD * S;
    const float* mrow = mask + (size_t)b * S;

    int srow[2], slc[2];
    #pragma unroll
    for (int u = 0; u < 2; ++u) {
        int s = u * 256 + tid;
        srow[u] = s >> 3;
        slc[u]  = (s & 7) ^ (srow[u] & 7);
    }

    #define STAGE(JT, NB)                                                     \
        _Pragma("unroll")                                                     \
        for (int u = 0; u < 2; ++u) {                                         \
            g2l16(Kg + (size_t)((JT) * 64 + srow[u]) * HD + slc[u] * 8,       \
                  Kbase + (NB) * 4096 + (u * 256 + w * 64) * 8);              \
            g2l16(Vg + (size_t)srow[u] * S + (JT) * 64 + slc[u] * 8,          \
                  Vbase + (NB) * 4096 + (u * 256 + w * 64) * 8);              \
        }

    STAGE(0, 0)

    f32x16 o0 = zero16(), o1 = zero16();
    float l_acc = 0.f;

    for (int jt = 0; jt < NT; ++jt) {
        const int cur = jt & 1;
        const float mv = mrow[jt * 64 + kh * 32 + l31];   // key = l31
        __syncthreads();               // drains own DMA + syncs all
        if (jt + 1 < NT) { STAGE(jt + 1, cur ^ 1) }

        const u16* Kc = Kbase + cur * 4096;
        const u16* Vc = Vbase + cur * 4096;

        // mask as MFMA: sc^T[key][qrow] = mt[key]
        const float mt = (1.0f - mv) * (-10000.0f * LOG2E);
        short8 mta = {};
        if (h5 == 0) mta[0] = (short)f2bf(mt);
        f32x16 sc = __builtin_amdgcn_mfma_f32_32x32x16_bf16(
            mta, oneb, zero16(), 0, 0, 0);

        // S^T += K . Q^T  (A = K-frag m=key, B = Q-frag n=qrow)
        {
            const int krow = kh * 32 + l31;
            const int sw = krow & 7;
            #pragma unroll
            for (int kc = 0; kc < 4; ++kc) {
                const short8 kb =
                    *(const short8*)&Kc[krow * 64 + ((kc * 2 + h5) ^ sw) * 8];
                sc = __builtin_amdgcn_mfma_f32_32x32x16_bf16(kb, qa[kc], sc, 0, 0, 0);
            }
        }

        // V^T A-frags (m = dim), read while exp burst runs
        short8 va[2][2];
        #pragma unroll
        for (int nt = 0; nt < 2; ++nt) {
            const int vrow = nt * 32 + l31;
            const int sw = vrow & 7;
            va[nt][0] = *(const short8*)&Vc[vrow * 64 + ((kh * 4 + h5) ^ sw) * 8];
            va[nt][1] = *(const short8*)&Vc[vrow * 64 + ((kh * 4 + 2 + h5) ^ sw) * 8];
        }

        // p = exp2(sc); accumulate l; pack bf16 pairs (reg r -> key
        // (r&3)+8*(r>>2)+4*h5, so d[i] = keys (2i,2i+1) of this lane's set)
        float p[16];
        #pragma unroll
        for (int r = 0; r < 16; ++r) {
            p[r] = __builtin_amdgcn_exp2f(sc[r]);
            l_acc += p[r];
        }
        u32 d[8];
        #pragma unroll
        for (int i = 0; i < 8; ++i)
            d[i] = ((u32)f2bf(p[2 * i + 1]) << 16) | (u32)f2bf(p[2 * i]);

        // half-wave exchange: h5=0 needs partner d0,d1,d4,d5;
        // h5=1 needs partner d2,d3,d6,d7. Sender supplies what receiver needs.
        u32 e0 = h5 ? d[0] : d[2];
        u32 e1 = h5 ? d[1] : d[3];
        u32 e2 = h5 ? d[4] : d[6];
        u32 e3 = h5 ? d[5] : d[7];
        u32 r0 = (u32)__shfl_xor((int)e0, 32, 64);
        u32 r1 = (u32)__shfl_xor((int)e1, 32, 64);
        u32 r2 = (u32)__shfl_xor((int)e2, 32, 64);
        u32 r3 = (u32)__shfl_xor((int)e3, 32, 64);

        // P^T B-frags: f0 -> keys 0..15 local, f1 -> keys 16..31
        pk4 f0, f1;
        if (h5) {
            f0.u = make_uint4(r0, r1, d[2], d[3]);
            f1.u = make_uint4(r2, r3, d[6], d[7]);
        } else {
            f0.u = make_uint4(d[0], d[1], r0, r1);
            f1.u = make_uint4(d[4], d[5], r2, r3);
        }

        // O^T += V^T . P^T
        o0 = __builtin_amdgcn_mfma_f32_32x32x16_bf16(va[0][0], f0.s, o0, 0, 0, 0);
        o0 = __builtin_amdgcn_mfma_f32_32x32x16_bf16(va[0][1], f1.s, o0, 0, 0, 0);
        o1 = __builtin_amdgcn_mfma_f32_32x32x16_bf16(va[1][0], f0.s, o1, 0, 0, 0);
        o1 = __builtin_amdgcn_mfma_f32_32x32x16_bf16(va[1][1], f1.s, o1, 0, 0, 0);
    }
    #undef STAGE

    // combine h5 halves of the row-sum (lane = qrow in both halves)
    l_acc += __shfl_xor(l_acc, 32, 64);

    __syncthreads();   // staging fully consumed -> reuse smem for combine
    float* cb = (float*)smem;             // bytes 0..16383: [r(32)][rh*64+lane]
    float* lb = (float*)(smem + 16384);   // byte 32768: [rh][qrow], 64 floats

    if (kh == 1) {
        #pragma unroll
        for (int r = 0; r < 16; ++r) {
            cb[r * 128 + rh * 64 + lane]        = o0[r];
            cb[(16 + r) * 128 + rh * 64 + lane] = o1[r];
        }
        if (h5 == 0) lb[rh * 32 + l31] = l_acc;
    }
    __syncthreads();
    if (kh == 0) {
        float lt = l_acc + lb[rh * 32 + l31];
        float inv = 1.0f / lt;
        const int s = q0 + rh * 32 + l31;
        u16* dst = ctx + ((size_t)b * S + s) * H + hh * 64;
        // dims: o0 reg r -> d = (r&3) + 8*(r>>2) + 4*h5 ; o1 -> +32
        #pragma unroll
        for (int g = 0; g < 4; ++g) {
            ushort4 pk0, pk1;
            pk0.x = f2bf((o0[4 * g + 0] + cb[(4 * g + 0) * 128 + rh * 64 + lane]) * inv);
            pk0.y = f2bf((o0[4 * g + 1] + cb[(4 * g + 1) * 128 + rh * 64 + lane]) * inv);
            pk0.z = f2bf((o0[4 * g + 2] + cb[(4 * g + 2) * 128 + rh * 64 + lane]) * inv);
            pk0.w = f2bf((o0[4 * g + 3] + cb[(4 * g + 3) * 128 + rh * 64 + lane]) * inv);
            *(ushort4*)(dst + 8 * g + 4 * h5) = pk0;
            pk1.x = f2bf((o1[4 * g + 0] + cb[(16 + 4 * g + 0) * 128 + rh * 64 + lane]) * inv);
            pk1.y = f2bf((o1[4 * g + 1] + cb[(16 + 4 * g + 1) * 128 + rh * 64 + lane]) * inv);
            pk1.z = f2bf((o1[4 * g + 2] + cb[(16 + 4 * g + 2) * 128 + rh * 64 + lane]) * inv);
            pk1.w = f2bf((o1[4 * g + 3] + cb[(16 + 4 * g + 3) * 128 + rh * 64 + lane]) * inv);
            *(ushort4*)(dst + 32 + 8 * g + 4 * h5) = pk1;
        }
    }
}

// ---------------------------------------------------------------------------
extern "C" void kernel_launch(void* const* d_in, const int* in_sizes, int n_in,
                              void* d_out, int out_size, void* d_ws, size_t ws_size,
                              hipStream_t stream)
{
    const float* hs   = (const float*)d_in[0];
    const float* mask = (const float*)d_in[1];
    const float* Wq   = (const float*)d_in[2];
    const float* bq   = (const float*)d_in[3];
    const float* Wk   = (const float*)d_in[4];
    const float* bk   = (const float*)d_in[5];
    const float* Wv   = (const float*)d_in[6];
    const float* bv   = (const float*)d_in[7];
    const float* Wo   = (const float*)d_in[8];
    const float* bo   = (const float*)d_in[9];
    const float* cosp = (const float*)d_in[10];
    const float* sinp = (const float*)d_in[11];
    float* out = (float*)d_out;

    const size_t per = (size_t)B * NH * S * HD;   // 3,145,728
    u16* ws    = (u16*)d_ws;
    u16* hsb   = ws;                              // bf16 hidden  [BS,H]
    u16* WTqkv = hsb + per;                       // bf16 [2304,768] (Q/K rotated)
    u16* WTo   = WTqkv + (size_t)3 * H * H;       // bf16 [768,768]
    u16* Qb    = WTo + (size_t)H * H;             // bf16 [B,NH,S,HD] final
    u16* Kb    = Qb + per;                        // bf16 final
    u16* VT    = Kb + per;                        // bf16 [B,NH,HD,S]
    u16* ctxb  = VT + per;                        // bf16 [BS,H]
    float* bqk2 = (float*)(ctxb + per);           // rotated biases [2*H]

    prep_kernel<<<576 + (BS * H) / 2048, 256, 0, stream>>>(
        hs, Wq, Wk, Wv, Wo, bq, bk, cosp, sinp, hsb, WTqkv, WTo, bqk2);

    gemm_qkv_kernel<<<(BS / 128) * (2304 / 128), 256, 0, stream>>>(
        hsb, WTqkv, bqk2, bv, Qb, Kb, VT);

    attn_mfma_kernel<<<(S / 64) * (B * NH), 256, 0, stream>>>(
        Qb, Kb, VT, mask, ctxb);

    gemm_out_kernel<<<(BS / 128) * (H / 64), 256, 0, stream>>>(
        ctxb, WTo, bo, out);
}